// Round 8
// baseline (1435.295 us; speedup 1.0000x reference)
//
#include <hip/hip_runtime.h>
#include <hip/hip_bf16.h>
#include <math.h>

// B=4, M=2048, D=512, H=8. Heads processed in groups of G (adaptive to ws_size; G=8 on this harness).

typedef __attribute__((ext_vector_type(8))) __bf16 bf16x8;
typedef __attribute__((ext_vector_type(4))) __bf16 bf16x4;
typedef __attribute__((ext_vector_type(4))) float f32x4;

#define MFMA16(a, b, c) __builtin_amdgcn_mfma_f32_16x16x32_bf16((a), (b), (c), 0, 0, 0)

__device__ __forceinline__ void g2l16(const void* g, void* l) {
  __builtin_amdgcn_global_load_lds((const __attribute__((address_space(1))) void*)g,
                                   (__attribute__((address_space(3))) void*)l, 16, 0, 0);
}

// ---------------- cast fp32 -> bf16 ----------------
__global__ void cast_bf16_k(const float* __restrict__ in, __bf16* __restrict__ out, int n4) {
  int i = blockIdx.x * blockDim.x + threadIdx.x;
  if (i >= n4) return;
  float4 f = reinterpret_cast<const float4*>(in)[i];
  bf16x4 o;
  o.x = (__bf16)f.x; o.y = (__bf16)f.y; o.z = (__bf16)f.z; o.w = (__bf16)f.w;
  reinterpret_cast<bf16x4*>(out)[i] = o;
}

// ---------------- RoPE tables, fp32 (faithful i-1 quirk) ----------------
__global__ void rope_tables_k(float* __restrict__ ct, float* __restrict__ st) {
  int idx = blockIdx.x * 256 + threadIdx.x;  // 2048*256
  int m = idx >> 8, j = idx & 255;
  float e = (-2.0f * ((float)j - 1.0f) / 512.0f) * 13.287712379549449f;  // log2(1e4)
  float theta = exp2f(e);
  float ang = (float)m * theta;
  float s, c;
  sincosf(ang, &s, &c);
  ct[idx] = c;
  st[idx] = s;
}

// ---------------- QKV projection (round-2 proven structure): z = which*G + hl ----------------
__global__ __launch_bounds__(256, 2) void qkv_gemm_k(
    const __bf16* __restrict__ Xb,
    const __bf16* __restrict__ Wqb, const __bf16* __restrict__ Wkb, const __bf16* __restrict__ Wvb,
    const float* __restrict__ ct, const float* __restrict__ st,
    __bf16* __restrict__ Q, __bf16* __restrict__ K, __bf16* __restrict__ V,
    int G, int lg, int h0) {
  const int z = blockIdx.z;
  const int which = z >> lg, hl = z & (G - 1);
  const int h = h0 + hl;
  const __bf16* W = (which == 0 ? Wqb : which == 1 ? Wkb : Wvb) + (size_t)h * 262144;
  __bf16* Out = (which == 0 ? Q : which == 1 ? K : V);

  const int mbase = blockIdx.x * 128;
  const int nbase = blockIdx.y * 128;

  __shared__ alignas(16) __bf16 As[128 * 64];
  __shared__ alignas(16) __bf16 Bs[128 * 64];

  const int tid = threadIdx.x;
  const int lane = tid & 63, wid = tid >> 6;
  const int wr = wid >> 1, wc = wid & 1;
  const int l15 = lane & 15, l4 = lane >> 4;

  f32x4 acc[4][4];
#pragma unroll
  for (int i = 0; i < 4; i++)
#pragma unroll
    for (int j = 0; j < 4; j++) acc[i][j] = f32x4{0.f, 0.f, 0.f, 0.f};

  for (int kt = 0; kt < 8; ++kt) {
    const int kb = kt * 64;
#pragma unroll
    for (int i = 0; i < 4; i++) {
      int chunk = i * 256 + tid;
      int row = chunk >> 3, col = (chunk & 7) * 8;
      g2l16(Xb + (size_t)(mbase + row) * 512 + kb + col, As + (i * 256 + (tid & ~63)) * 8);
    }
#pragma unroll
    for (int i = 0; i < 4; i++) {
      int chunk = i * 256 + tid;
      int row = chunk >> 3, col = (chunk & 7) * 8;
      g2l16(W + (size_t)(nbase + row) * 512 + kb + col, Bs + (i * 256 + (tid & ~63)) * 8);
    }
    __syncthreads();
#pragma unroll
    for (int kk = 0; kk < 2; ++kk) {
      bf16x8 a[4], b[4];
#pragma unroll
      for (int i = 0; i < 4; i++)
        a[i] = *reinterpret_cast<const bf16x8*>(As + (wr * 64 + i * 16 + l15) * 64 + kk * 32 + l4 * 8);
#pragma unroll
      for (int j = 0; j < 4; j++)
        b[j] = *reinterpret_cast<const bf16x8*>(Bs + (wc * 64 + j * 16 + l15) * 64 + kk * 32 + l4 * 8);
#pragma unroll
      for (int i = 0; i < 4; i++)
#pragma unroll
        for (int j = 0; j < 4; j++) acc[i][j] = MFMA16(a[i], b[j], acc[i][j]);
    }
    __syncthreads();
  }

  const bool dorope = (which < 2);
#pragma unroll
  for (int i = 0; i < 4; i++) {
#pragma unroll
    for (int j = 0; j < 4; j++) {
      const int col = nbase + wc * 64 + j * 16 + l15;
#pragma unroll
      for (int r = 0; r < 4; r++) {
        const int rowg = mbase + wr * 64 + i * 16 + l4 * 4 + r;
        const int b_ = rowg >> 11, m = rowg & 2047;
        float v = acc[i][j][r];
        if (dorope) {
          float pv = __shfl_xor(v, 1, 64);  // partner column (col^1) in lane^1
          float c = ct[m * 256 + (col >> 1)];
          float s = st[m * 256 + (col >> 1)];
          v = (col & 1) ? (v * c - pv * s) : (v * c + pv * s);
        }
        Out[(size_t)((b_ * G + hl) * 2048 + m) * 512 + col] = (__bf16)v;
      }
    }
  }
}

// ---------------- V transpose: [(b*G+hl)][m][d] -> [(b*G+hl)][d][m] ----------------
__global__ void transpose_v_k(const __bf16* __restrict__ V, __bf16* __restrict__ VT) {
  __shared__ __bf16 sm[32][33];
  const int bh = blockIdx.z;
  const int mb = blockIdx.x * 32, db = blockIdx.y * 32;
  const int tx = threadIdx.x, ty = threadIdx.y;  // 32 x 8
  const __bf16* Vg = V + (size_t)bh * (2048 * 512);
  __bf16* Tg = VT + (size_t)bh * (512 * 2048);
#pragma unroll
  for (int i = 0; i < 4; i++) sm[ty + i * 8][tx] = Vg[(size_t)(mb + ty + i * 8) * 512 + db + tx];
  __syncthreads();
#pragma unroll
  for (int i = 0; i < 4; i++) Tg[(size_t)(db + ty + i * 8) * 2048 + mb + tx] = sm[tx][ty + i * 8];
}

// ---------------- causal flash attention v7 ----------------
// 8 waves, QBLK=128, KBLK=32, balanced pairing (R7). New: PV d-split — wave w owns
// d-slice [64w,64w+64) of O for ALL 128 q rows; P shared via Ps[128][36]; rescale
// factors shared via Al[128] + __syncthreads_or defer-max. V reg-staged into padded
// [512][36] (conflict-free). K/V(kt+1) prefetch issued post-mid-barrier (drain-free).
__global__ __launch_bounds__(512) void flash_attn_k(
    const __bf16* __restrict__ Q, const __bf16* __restrict__ K, const __bf16* __restrict__ VT,
    __bf16* __restrict__ O, int G, int lg) {  // O: [B, M, G*512] bf16
  const int bhN = 4 * G;
  const int L = blockIdx.x + 16 * blockIdx.y;
  const int half = L / (8 * bhN);
  const int r_ = L % (8 * bhN);
  const int bh = r_ % bhN;
  const int p_ = r_ / bhN;  // 0..7
  const int qblk = half ? (15 - p_) : p_;
  const int b = bh >> lg, hl = bh & (G - 1);
  const int tid = threadIdx.x, lane = tid & 63, wid = tid >> 6;
  const int l15 = lane & 15, l4 = lane >> 4;
  const int qbase = qblk * 128;
  const int qw = qbase + wid * 16;  // softmax rows owned by this wave

  __shared__ alignas(16) __bf16 Ks[32 * 512];   // 32KB, 3-bit XOR chunk swizzle
  __shared__ alignas(16) __bf16 Vts[512 * 36];  // 36KB, [d][k] padded (conflict-free)
  __shared__ alignas(16) __bf16 Ps[128 * 36];   // 9KB, shared P, padded
  __shared__ alignas(16) float Al[128];         // rescale factors / final 1/l

  const __bf16* Qg = Q + ((size_t)bh * 2048 + qw) * 512;
  const __bf16* Kg = K + (size_t)bh * 2048 * 512;
  const __bf16* Tg = VT + (size_t)bh * 512 * 2048;
  const float scale = 0.04419417382415922f;  // 1/sqrt(512)

  bf16x8 qf[16];
#pragma unroll
  for (int c = 0; c < 16; c++)
    qf[c] = *reinterpret_cast<const bf16x8*>(Qg + l15 * 512 + c * 32 + l4 * 8);

  f32x4 acc[8][4];  // O[128 q][d-slice 64] distributed: acc[qf][df]
#pragma unroll
  for (int i = 0; i < 8; i++)
#pragma unroll
    for (int j = 0; j < 4; j++) acc[i][j] = f32x4{0.f, 0.f, 0.f, 0.f};
  float mrow[4] = {-INFINITY, -INFINITY, -INFINITY, -INFINITY};
  float lrow[4] = {0.f, 0.f, 0.f, 0.f};

  const int nt = 4 * qblk + 4;
  bf16x8 vreg[4];

  auto stageK = [&](int kt2) {
#pragma unroll
    for (int i = 0; i < 4; i++) {
      int chunk = i * 512 + tid;
      int row = chunk >> 6, c16 = chunk & 63;
      g2l16(Kg + (size_t)(kt2 * 32 + row) * 512 + ((c16 ^ (row & 7)) << 3),
            Ks + (i * 512 + (tid & ~63)) * 8);
    }
  };
  auto loadV = [&](int kt2) {
#pragma unroll
    for (int i = 0; i < 4; i++) {
      int chunk = i * 512 + tid;
      vreg[i] = *reinterpret_cast<const bf16x8*>(
          Tg + (size_t)(chunk >> 2) * 2048 + kt2 * 32 + (chunk & 3) * 8);
    }
  };

  stageK(0);
  loadV(0);

  for (int kt = 0; kt < nt; ++kt) {
    const int kb = kt * 32;
    __syncthreads();  // top: prev PV done (Vts/Ks free); drains K(kt)/V(kt) loads (issued a phase ago)

    // commit V(kt) regs -> padded LDS
#pragma unroll
    for (int i = 0; i < 4; i++) {
      int chunk = i * 512 + tid;
      *reinterpret_cast<bf16x8*>(&Vts[(chunk >> 2) * 36 + (chunk & 3) * 8]) = vreg[i];
    }

    // ---- QK^T for this wave's 16 q rows ----
    f32x4 sv0 = f32x4{0.f, 0.f, 0.f, 0.f}, sv1 = f32x4{0.f, 0.f, 0.f, 0.f};
    __builtin_amdgcn_s_setprio(1);
#pragma unroll
    for (int c = 0; c < 16; c++) {
      const int off = c * 32 + l4 * 8;
      const int r0 = l15, r1 = 16 + l15;
      bf16x8 b0 = *reinterpret_cast<const bf16x8*>(Ks + r0 * 512 + (off ^ ((r0 & 7) << 3)));
      bf16x8 b1 = *reinterpret_cast<const bf16x8*>(Ks + r1 * 512 + (off ^ ((r1 & 7) << 3)));
      sv0 = MFMA16(qf[c], b0, sv0);
      sv1 = MFMA16(qf[c], b1, sv1);
    }
    __builtin_amdgcn_s_setprio(0);

    // ---- online softmax (defer-max THR=8) ----
    float mx[4];
#pragma unroll
    for (int r = 0; r < 4; r++) {
      const int qg = qw + l4 * 4 + r;
      float s0 = sv0[r] * scale;
      float s1 = sv1[r] * scale;
      if (kb + l15 > qg) s0 = -INFINITY;
      if (kb + 16 + l15 > qg) s1 = -INFINITY;
      sv0[r] = s0; sv1[r] = s1;
      float m_ = fmaxf(s0, s1);
      m_ = fmaxf(m_, __shfl_xor(m_, 1, 64));
      m_ = fmaxf(m_, __shfl_xor(m_, 2, 64));
      m_ = fmaxf(m_, __shfl_xor(m_, 4, 64));
      m_ = fmaxf(m_, __shfl_xor(m_, 8, 64));
      mx[r] = m_;
    }
    bool need = (mx[0] > mrow[0] + 8.f) || (mx[1] > mrow[1] + 8.f) ||
                (mx[2] > mrow[2] + 8.f) || (mx[3] > mrow[3] + 8.f);
    float al[4] = {1.f, 1.f, 1.f, 1.f};
    if (need) {
#pragma unroll
      for (int r = 0; r < 4; r++) {
        float mn = fmaxf(mrow[r], mx[r]);
        al[r] = __expf(mrow[r] - mn);
        lrow[r] *= al[r];
        mrow[r] = mn;
      }
    }
#pragma unroll
    for (int r = 0; r < 4; r++) {
      float p0 = __expf(sv0[r] - mrow[r]);
      float p1 = __expf(sv1[r] - mrow[r]);
      float rs = p0 + p1;
      rs += __shfl_xor(rs, 1, 64);
      rs += __shfl_xor(rs, 2, 64);
      rs += __shfl_xor(rs, 4, 64);
      rs += __shfl_xor(rs, 8, 64);
      lrow[r] += rs;
      const int prow = wid * 16 + l4 * 4 + r;
      Ps[prow * 36 + l15] = (__bf16)p0;
      Ps[prow * 36 + 16 + l15] = (__bf16)p1;
      if (l15 == 0) Al[prow] = al[r];
    }

    int anyresc = __syncthreads_or((int)need);  // mid barrier: Ps/Al/Vts visible

    // prefetch next tile (flies through PV + next QK; drained at next top barrier)
    if (kt + 1 < nt) {
      stageK(kt + 1);
      loadV(kt + 1);
    }

    // ---- rescale O by shared alphas ----
    if (anyresc) {
#pragma unroll
      for (int i = 0; i < 8; i++) {
        f32x4 a4 = *reinterpret_cast<const f32x4*>(&Al[i * 16 + l4 * 4]);
#pragma unroll
        for (int j = 0; j < 4; j++) {
#pragma unroll
          for (int r = 0; r < 4; r++) acc[i][j][r] *= a4[r];
        }
      }
    }

    // ---- PV: wave owns d-slice [64*wid, +64) for all 128 q rows ----
    const int d0 = wid * 64;
    __builtin_amdgcn_s_setprio(1);
#pragma unroll
    for (int qh = 0; qh < 2; ++qh) {
      bf16x8 pA[4];
#pragma unroll
      for (int i = 0; i < 4; i++)
        pA[i] = *reinterpret_cast<const bf16x8*>(&Ps[((qh * 4 + i) * 16 + l15) * 36 + l4 * 8]);
#pragma unroll
      for (int j = 0; j < 4; j++) {
        bf16x8 vB = *reinterpret_cast<const bf16x8*>(&Vts[(d0 + j * 16 + l15) * 36 + l4 * 8]);
#pragma unroll
        for (int i = 0; i < 4; i++)
          acc[qh * 4 + i][j] = MFMA16(pA[i], vB, acc[qh * 4 + i][j]);
      }
    }
    __builtin_amdgcn_s_setprio(0);
  }

  // ---- epilogue: share 1/l, write O ----
  __syncthreads();  // all PV done; Al free for reuse
#pragma unroll
  for (int r = 0; r < 4; r++)
    if (l15 == 0) Al[wid * 16 + l4 * 4 + r] = 1.0f / lrow[r];
  __syncthreads();
  const int d0 = wid * 64;
#pragma unroll
  for (int i = 0; i < 8; i++) {
    f32x4 inv4 = *reinterpret_cast<const f32x4*>(&Al[i * 16 + l4 * 4]);
#pragma unroll
    for (int r = 0; r < 4; r++) {
      const int qg = qbase + i * 16 + l4 * 4 + r;
      __bf16* Og = O + ((size_t)(b * 2048 + qg) * (512 * G) + hl * 512 + d0);
#pragma unroll
      for (int j = 0; j < 4; j++) Og[j * 16 + l15] = (__bf16)(acc[i][j][r] * inv4[r]);
    }
  }
}

// ---------------- output projection (per group, accumulating) ----------------
__global__ __launch_bounds__(256, 2) void out_gemm_k(
    const __bf16* __restrict__ A, const __bf16* __restrict__ Wo,
    const float* __restrict__ bias, float* __restrict__ Y, int G, int first) {
  const int AS = 512 * G;
  const int mbase = blockIdx.x * 128, nbase = blockIdx.y * 128;
  __shared__ alignas(16) __bf16 As[128 * 64];
  __shared__ alignas(16) __bf16 Bs[128 * 64];
  const int tid = threadIdx.x;
  const int lane = tid & 63, wid = tid >> 6;
  const int wr = wid >> 1, wc = wid & 1;
  const int l15 = lane & 15, l4 = lane >> 4;

  f32x4 acc[4][4];
#pragma unroll
  for (int i = 0; i < 4; i++)
#pragma unroll
    for (int j = 0; j < 4; j++) acc[i][j] = f32x4{0.f, 0.f, 0.f, 0.f};

  const int nkt = 8 * G;
  for (int kt = 0; kt < nkt; ++kt) {
    const int kb = kt * 64;
#pragma unroll
    for (int i = 0; i < 4; i++) {
      int chunk = i * 256 + tid;
      int row = chunk >> 3, col = (chunk & 7) * 8;
      g2l16(A + (size_t)(mbase + row) * AS + kb + col, As + (i * 256 + (tid & ~63)) * 8);
    }
#pragma unroll
    for (int i = 0; i < 4; i++) {
      int chunk = i * 256 + tid;
      int row = chunk >> 3, col = (chunk & 7) * 8;
      g2l16(Wo + (size_t)(nbase + row) * 4096 + kb + col, Bs + (i * 256 + (tid & ~63)) * 8);
    }
    __syncthreads();
#pragma unroll
    for (int kk = 0; kk < 2; ++kk) {
      bf16x8 a[4], b[4];
#pragma unroll
      for (int i = 0; i < 4; i++)
        a[i] = *reinterpret_cast<const bf16x8*>(As + (wr * 64 + i * 16 + l15) * 64 + kk * 32 + l4 * 8);
#pragma unroll
      for (int j = 0; j < 4; j++)
        b[j] = *reinterpret_cast<const bf16x8*>(Bs + (wc * 64 + j * 16 + l15) * 64 + kk * 32 + l4 * 8);
#pragma unroll
      for (int i = 0; i < 4; i++)
#pragma unroll
        for (int j = 0; j < 4; j++) acc[i][j] = MFMA16(a[i], b[j], acc[i][j]);
    }
    __syncthreads();
  }

#pragma unroll
  for (int i = 0; i < 4; i++) {
#pragma unroll
    for (int j = 0; j < 4; j++) {
      const int col = nbase + wc * 64 + j * 16 + l15;
#pragma unroll
      for (int r = 0; r < 4; r++) {
        const int row = mbase + wr * 64 + i * 16 + l4 * 4 + r;
        float prev = first ? bias[col] : Y[(size_t)row * 512 + col];
        Y[(size_t)row * 512 + col] = prev + acc[i][j][r];
      }
    }
  }
}

extern "C" void kernel_launch(void* const* d_in, const int* in_sizes, int n_in,
                              void* d_out, int out_size, void* d_ws, size_t ws_size,
                              hipStream_t stream) {
  (void)in_sizes; (void)n_in; (void)out_size;
  const float* x = (const float*)d_in[0];
  const float* wq = (const float*)d_in[1];
  const float* wk = (const float*)d_in[2];
  const float* wv = (const float*)d_in[3];
  const float* wo = (const float*)d_in[4];
  const float* bo = (const float*)d_in[5];
  float* y = (float*)d_out;

  char* base = (char*)d_ws;
  size_t off = 0;
  auto alloc = [&](size_t bytes) -> void* {
    void* p = base + off;
    off += (bytes + 255) & ~(size_t)255;
    return p;
  };
  __bf16* xb = (__bf16*)alloc((size_t)8192 * 512 * 2);
  __bf16* wqb = (__bf16*)alloc((size_t)8 * 512 * 512 * 2);
  __bf16* wkb = (__bf16*)alloc((size_t)8 * 512 * 512 * 2);
  __bf16* wvb = (__bf16*)alloc((size_t)8 * 512 * 512 * 2);
  __bf16* wob = (__bf16*)alloc((size_t)512 * 4096 * 2);
  float* ct = (float*)alloc((size_t)2048 * 256 * 4);
  float* st = (float*)alloc((size_t)2048 * 256 * 4);
  const size_t persist = off;

  // choose largest head-group G with persist + 4 * (G*4*2048*512*2) <= ws_size
  int G = 0, lg = 0;
  for (int g = 8, l = 3; g >= 1; g >>= 1, --l) {
    size_t T = ((size_t)g * 4 * 2048 * 512 * 2 + 255) & ~(size_t)255;
    if (persist + 4 * T <= ws_size) { G = g; lg = l; break; }
  }
  if (G == 0) return;

  size_t T = ((size_t)G * 4 * 2048 * 512 * 2 + 255) & ~(size_t)255;
  __bf16* Qb = (__bf16*)(base + persist);
  __bf16* Kb = (__bf16*)(base + persist + T);
  __bf16* Vb = (__bf16*)(base + persist + 2 * T);
  __bf16* VTb = (__bf16*)(base + persist + 3 * T);
  __bf16* Ob = Vb;  // V dead after transpose; O ([B,M,G*512]) reuses it

  cast_bf16_k<<<4096, 256, 0, stream>>>(x, xb, 1048576);
  cast_bf16_k<<<2048, 256, 0, stream>>>(wq, wqb, 524288);
  cast_bf16_k<<<2048, 256, 0, stream>>>(wk, wkb, 524288);
  cast_bf16_k<<<2048, 256, 0, stream>>>(wv, wvb, 524288);
  cast_bf16_k<<<2048, 256, 0, stream>>>(wo, wob, 524288);
  rope_tables_k<<<2048, 256, 0, stream>>>(ct, st);

  for (int h0 = 0; h0 < 8; h0 += G) {
    qkv_gemm_k<<<dim3(64, 4, 3 * G), 256, 0, stream>>>(xb, wqb, wkb, wvb, ct, st,
                                                       Qb, Kb, Vb, G, lg, h0);
    transpose_v_k<<<dim3(64, 16, 4 * G), dim3(32, 8), 0, stream>>>(Vb, VTb);
    flash_attn_k<<<dim3(16, 4 * G), 512, 0, stream>>>(Qb, Kb, VTb, Ob, G, lg);
    out_gemm_k<<<dim3(64, 4), 256, 0, stream>>>(Ob, wob + h0 * 512, bo, y, G, h0 == 0);
  }
}

// Round 10
// 942.125 us; speedup vs baseline: 1.5235x; 1.5235x over previous
//
#include <hip/hip_runtime.h>
#include <hip/hip_bf16.h>
#include <math.h>

// B=4, M=2048, D=512, H=8. Heads processed in groups of G (adaptive to ws_size; G=4 on this harness).

typedef __attribute__((ext_vector_type(8))) __bf16 bf16x8;
typedef __attribute__((ext_vector_type(4))) __bf16 bf16x4;
typedef __attribute__((ext_vector_type(4))) float f32x4;

#define MFMA16(a, b, c) __builtin_amdgcn_mfma_f32_16x16x32_bf16((a), (b), (c), 0, 0, 0)

__device__ __forceinline__ void g2l16(const void* g, void* l) {
  __builtin_amdgcn_global_load_lds((const __attribute__((address_space(1))) void*)g,
                                   (__attribute__((address_space(3))) void*)l, 16, 0, 0);
}

// ---------------- fused prep: all fp32->bf16 casts + RoPE tables ----------------
__global__ void prep_k(const float* __restrict__ x, const float* __restrict__ wq,
                       const float* __restrict__ wk, const float* __restrict__ wv,
                       const float* __restrict__ wo,
                       __bf16* __restrict__ xb, __bf16* __restrict__ wqb,
                       __bf16* __restrict__ wkb, __bf16* __restrict__ wvb,
                       __bf16* __restrict__ wob,
                       float* __restrict__ ct, float* __restrict__ st) {
  int i = blockIdx.x * 256 + threadIdx.x;
  if (i < 3145728) {  // 3.1M float4 casts: x(1048576) wq/wk/wv/wo(524288 each)
    const float* src;
    __bf16* dst;
    int off = i;
    if (i < 1048576) { src = x; dst = xb; }
    else if (i < 1572864) { src = wq; dst = wqb; off = i - 1048576; }
    else if (i < 2097152) { src = wk; dst = wkb; off = i - 1572864; }
    else if (i < 2621440) { src = wv; dst = wvb; off = i - 2097152; }
    else { src = wo; dst = wob; off = i - 2621440; }
    float4 f = reinterpret_cast<const float4*>(src)[off];
    bf16x4 o;
    o.x = (__bf16)f.x; o.y = (__bf16)f.y; o.z = (__bf16)f.z; o.w = (__bf16)f.w;
    reinterpret_cast<bf16x4*>(dst)[off] = o;
  } else {  // RoPE tables, faithful i-1 quirk
    int idx = i - 3145728;  // 0..524287 = 2048*256
    int m = idx >> 8, j = idx & 255;
    float e = (-2.0f * ((float)j - 1.0f) / 512.0f) * 13.287712379549449f;  // log2(1e4)
    float theta = exp2f(e);
    float ang = (float)m * theta;
    float s, c;
    sincosf(ang, &s, &c);
    ct[idx] = c;
    st[idx] = s;
  }
}

// ---------------- QKV projection: z = which*G + hl; V written directly transposed ----------------
__global__ __launch_bounds__(256, 2) void qkv_gemm_k(
    const __bf16* __restrict__ Xb,
    const __bf16* __restrict__ Wqb, const __bf16* __restrict__ Wkb, const __bf16* __restrict__ Wvb,
    const float* __restrict__ ct, const float* __restrict__ st,
    __bf16* __restrict__ Q, __bf16* __restrict__ K, __bf16* __restrict__ VT,
    int G, int lg, int h0) {
  const int z = blockIdx.z;
  const int which = z >> lg, hl = z & (G - 1);
  const int h = h0 + hl;
  const __bf16* W = (which == 0 ? Wqb : which == 1 ? Wkb : Wvb) + (size_t)h * 262144;

  const int mbase = blockIdx.x * 128;
  const int nbase = blockIdx.y * 128;

  __shared__ alignas(16) __bf16 As[128 * 64];
  __shared__ alignas(16) __bf16 Bs[128 * 64];

  const int tid = threadIdx.x;
  const int lane = tid & 63, wid = tid >> 6;
  const int wr = wid >> 1, wc = wid & 1;
  const int l15 = lane & 15, l4 = lane >> 4;

  f32x4 acc[4][4];
#pragma unroll
  for (int i = 0; i < 4; i++)
#pragma unroll
    for (int j = 0; j < 4; j++) acc[i][j] = f32x4{0.f, 0.f, 0.f, 0.f};

  for (int kt = 0; kt < 8; ++kt) {
    const int kb = kt * 64;
#pragma unroll
    for (int i = 0; i < 4; i++) {
      int chunk = i * 256 + tid;
      int row = chunk >> 3, col = (chunk & 7) * 8;
      g2l16(Xb + (size_t)(mbase + row) * 512 + kb + col, As + (i * 256 + (tid & ~63)) * 8);
    }
#pragma unroll
    for (int i = 0; i < 4; i++) {
      int chunk = i * 256 + tid;
      int row = chunk >> 3, col = (chunk & 7) * 8;
      g2l16(W + (size_t)(nbase + row) * 512 + kb + col, Bs + (i * 256 + (tid & ~63)) * 8);
    }
    __syncthreads();
#pragma unroll
    for (int kk = 0; kk < 2; ++kk) {
      bf16x8 a[4], b[4];
#pragma unroll
      for (int i = 0; i < 4; i++)
        a[i] = *reinterpret_cast<const bf16x8*>(As + (wr * 64 + i * 16 + l15) * 64 + kk * 32 + l4 * 8);
#pragma unroll
      for (int j = 0; j < 4; j++)
        b[j] = *reinterpret_cast<const bf16x8*>(Bs + (wc * 64 + j * 16 + l15) * 64 + kk * 32 + l4 * 8);
#pragma unroll
      for (int i = 0; i < 4; i++)
#pragma unroll
        for (int j = 0; j < 4; j++) acc[i][j] = MFMA16(a[i], b[j], acc[i][j]);
    }
    __syncthreads();
  }

  if (which == 2) {
    // V: write transposed directly. acc r-values are 4 consecutive m at fixed d=col
    // -> 8B contiguous bf16x4 store into VT[(b*G+hl)][d][m].
    const int b_ = mbase >> 11;
    const int mloc = mbase & 2047;
    __bf16* Tgw = VT + (size_t)(b_ * G + hl) * 512 * 2048;
#pragma unroll
    for (int i = 0; i < 4; i++) {
#pragma unroll
      for (int j = 0; j < 4; j++) {
        const int col = nbase + wc * 64 + j * 16 + l15;
        const int m0 = mloc + wr * 64 + i * 16 + l4 * 4;
        bf16x4 pk;
        pk.x = (__bf16)acc[i][j][0];
        pk.y = (__bf16)acc[i][j][1];
        pk.z = (__bf16)acc[i][j][2];
        pk.w = (__bf16)acc[i][j][3];
        *reinterpret_cast<bf16x4*>(&Tgw[(size_t)col * 2048 + m0]) = pk;
      }
    }
  } else {
    // Q/K: RoPE + row-major write [(b*G+hl), m, d]
    __bf16* Out = which ? K : Q;
#pragma unroll
    for (int i = 0; i < 4; i++) {
#pragma unroll
      for (int j = 0; j < 4; j++) {
        const int col = nbase + wc * 64 + j * 16 + l15;
#pragma unroll
        for (int r = 0; r < 4; r++) {
          const int rowg = mbase + wr * 64 + i * 16 + l4 * 4 + r;
          const int b_ = rowg >> 11, m = rowg & 2047;
          float v = acc[i][j][r];
          float pv = __shfl_xor(v, 1, 64);  // partner column (col^1) in lane^1
          float c = ct[m * 256 + (col >> 1)];
          float s = st[m * 256 + (col >> 1)];
          v = (col & 1) ? (v * c - pv * s) : (v * c + pv * s);
          Out[(size_t)((b_ * G + hl) * 2048 + m) * 512 + col] = (__bf16)v;
        }
      }
    }
  }
}

// ---------------- causal flash attention (R7: proven best, + __expf) ----------------
// 8 waves x 16 q-rows (QBLK=128), KBLK=32. Grid 16 x 4G. Balanced pairing: CU c hosts
// L=c and L=c+8*bhN with complementary q-tiles -> 68 tiles per CU, 2 co-resident blocks.
__global__ __launch_bounds__(512) void flash_attn_k(
    const __bf16* __restrict__ Q, const __bf16* __restrict__ K, const __bf16* __restrict__ VT,
    __bf16* __restrict__ O, int G, int lg) {  // O: [B, M, G*512] bf16
  const int bhN = 4 * G;
  const int L = blockIdx.x + 16 * blockIdx.y;
  const int half = L / (8 * bhN);
  const int r_ = L % (8 * bhN);
  const int bh = r_ % bhN;
  const int p_ = r_ / bhN;  // 0..7
  const int qblk = half ? (15 - p_) : p_;
  const int b = bh >> lg, hl = bh & (G - 1);
  const int tid = threadIdx.x, lane = tid & 63, wid = tid >> 6;
  const int l15 = lane & 15, l4 = lane >> 4;
  const int qw = qblk * 128 + wid * 16;

  __shared__ alignas(16) __bf16 Ks[32 * 512];    // 32KB, 3-bit XOR swizzle on 16B chunks
  __shared__ alignas(16) __bf16 Vts[512 * 32];   // 32KB, 2-bit XOR swizzle
  __shared__ alignas(16) __bf16 Ps[8][16 * 32];  // 8KB, wave-private P

  const __bf16* Qg = Q + ((size_t)bh * 2048 + qw) * 512;
  const __bf16* Kg = K + (size_t)bh * 2048 * 512;
  const __bf16* Tg = VT + (size_t)bh * 512 * 2048;

  bf16x8 qf[16];
#pragma unroll
  for (int c = 0; c < 16; c++)
    qf[c] = *reinterpret_cast<const bf16x8*>(Qg + l15 * 512 + c * 32 + l4 * 8);

  f32x4 acc[32];
#pragma unroll
  for (int n = 0; n < 32; n++) acc[n] = f32x4{0.f, 0.f, 0.f, 0.f};
  float mrow[4] = {-INFINITY, -INFINITY, -INFINITY, -INFINITY};
  float lrow[4] = {0.f, 0.f, 0.f, 0.f};

  const float scale = 0.04419417382415922f;  // 1/sqrt(512)
  const int ntiles = qblk * 4 + 4;

  for (int kt = 0; kt < ntiles; ++kt) {
    const int kb = kt * 32;
#pragma unroll
    for (int i = 0; i < 4; i++) {
      int chunk = i * 512 + tid;
      int row = chunk >> 6, c16 = chunk & 63;
      g2l16(Kg + (size_t)(kb + row) * 512 + ((c16 ^ (row & 7)) << 3),
            Ks + (i * 512 + (tid & ~63)) * 8);
    }
#pragma unroll
    for (int i = 0; i < 4; i++) {
      int chunk = i * 512 + tid;
      int row = chunk >> 2, c4 = chunk & 3;
      g2l16(Tg + (size_t)row * 2048 + kb + ((c4 ^ (row & 3)) << 3),
            Vts + (i * 512 + (tid & ~63)) * 8);
    }
    __syncthreads();

    f32x4 sv0 = f32x4{0.f, 0.f, 0.f, 0.f}, sv1 = f32x4{0.f, 0.f, 0.f, 0.f};
#pragma unroll
    for (int c = 0; c < 16; c++) {
      const int off = c * 32 + l4 * 8;
      const int r0 = l15, r1 = 16 + l15;
      bf16x8 b0 = *reinterpret_cast<const bf16x8*>(Ks + r0 * 512 + (off ^ ((r0 & 7) << 3)));
      bf16x8 b1 = *reinterpret_cast<const bf16x8*>(Ks + r1 * 512 + (off ^ ((r1 & 7) << 3)));
      sv0 = MFMA16(qf[c], b0, sv0);
      sv1 = MFMA16(qf[c], b1, sv1);
    }

    float alpha[4];
#pragma unroll
    for (int r = 0; r < 4; r++) {
      const int qg = qw + l4 * 4 + r;
      float s0 = sv0[r] * scale;
      float s1 = sv1[r] * scale;
      if (kb + l15 > qg) s0 = -INFINITY;
      if (kb + 16 + l15 > qg) s1 = -INFINITY;
      float mx = fmaxf(s0, s1);
      mx = fmaxf(mx, __shfl_xor(mx, 1, 64));
      mx = fmaxf(mx, __shfl_xor(mx, 2, 64));
      mx = fmaxf(mx, __shfl_xor(mx, 4, 64));
      mx = fmaxf(mx, __shfl_xor(mx, 8, 64));
      const float mn = fmaxf(mrow[r], mx);
      const float p0 = __expf(s0 - mn);
      const float p1 = __expf(s1 - mn);
      const float a_ = __expf(mrow[r] - mn);
      float rs = p0 + p1;
      rs += __shfl_xor(rs, 1, 64);
      rs += __shfl_xor(rs, 2, 64);
      rs += __shfl_xor(rs, 4, 64);
      rs += __shfl_xor(rs, 8, 64);
      lrow[r] = lrow[r] * a_ + rs;
      mrow[r] = mn;
      alpha[r] = a_;
      __bf16* P = &Ps[wid][0];
      P[(l4 * 4 + r) * 32 + l15] = (__bf16)p0;
      P[(l4 * 4 + r) * 32 + 16 + l15] = (__bf16)p1;
    }
#pragma unroll
    for (int n = 0; n < 32; n++) {
#pragma unroll
      for (int r = 0; r < 4; r++) acc[n][r] *= alpha[r];
    }
    bf16x8 pf = *reinterpret_cast<const bf16x8*>(&Ps[wid][0] + l15 * 32 + l4 * 8);
#pragma unroll
    for (int n = 0; n < 32; n++) {
      const int row = n * 16 + l15;
      bf16x8 vb = *reinterpret_cast<const bf16x8*>(Vts + row * 32 + ((l4 * 8) ^ ((row & 3) << 3)));
      acc[n] = MFMA16(pf, vb, acc[n]);
    }
    __syncthreads();
  }

#pragma unroll
  for (int r = 0; r < 4; r++) {
    const int qg = qw + l4 * 4 + r;
    const float inv = 1.0f / lrow[r];
    __bf16* Og = O + ((size_t)(b * 2048 + qg) * (512 * G) + hl * 512);
#pragma unroll
    for (int n = 0; n < 32; n++) Og[n * 16 + l15] = (__bf16)(acc[n][r] * inv);
  }
}

// ---------------- output projection: 128x64 tile, grid (64,8) -> 2 blocks/CU TLP ----------------
// NOTE: wob row stride is ALWAYS 4096 ([512][H*D]); A (O) row stride is 512*G.
__global__ __launch_bounds__(256) void out_gemm_k(
    const __bf16* __restrict__ A, const __bf16* __restrict__ Wo,
    const float* __restrict__ bias, float* __restrict__ Y, int G, int first) {
  const int AS = 512 * G;
  const int mbase = blockIdx.x * 128, nbase = blockIdx.y * 64;
  __shared__ alignas(16) __bf16 As[128 * 64];  // 16KB
  __shared__ alignas(16) __bf16 Bs[64 * 64];   // 8KB
  const int tid = threadIdx.x;
  const int lane = tid & 63, wid = tid >> 6;
  const int wr = wid >> 1, wc = wid & 1;
  const int l15 = lane & 15, l4 = lane >> 4;

  f32x4 acc[4][2];
#pragma unroll
  for (int i = 0; i < 4; i++)
#pragma unroll
    for (int j = 0; j < 2; j++) acc[i][j] = f32x4{0.f, 0.f, 0.f, 0.f};

  const int nkt = 8 * G;
  for (int kt = 0; kt < nkt; ++kt) {
    const int kb = kt * 64;
#pragma unroll
    for (int i = 0; i < 4; i++) {
      int chunk = i * 256 + tid;
      int row = chunk >> 3, col = (chunk & 7) * 8;
      g2l16(A + (size_t)(mbase + row) * AS + kb + col, As + (i * 256 + (tid & ~63)) * 8);
    }
#pragma unroll
    for (int i = 0; i < 2; i++) {
      int chunk = i * 256 + tid;
      int row = chunk >> 3, col = (chunk & 7) * 8;
      g2l16(Wo + (size_t)(nbase + row) * 4096 + kb + col, Bs + (i * 256 + (tid & ~63)) * 8);
    }
    __syncthreads();
#pragma unroll
    for (int kk = 0; kk < 2; ++kk) {
      bf16x8 a[4], b[2];
#pragma unroll
      for (int i = 0; i < 4; i++)
        a[i] = *reinterpret_cast<const bf16x8*>(As + (wr * 64 + i * 16 + l15) * 64 + kk * 32 + l4 * 8);
#pragma unroll
      for (int j = 0; j < 2; j++)
        b[j] = *reinterpret_cast<const bf16x8*>(Bs + (wc * 32 + j * 16 + l15) * 64 + kk * 32 + l4 * 8);
#pragma unroll
      for (int i = 0; i < 4; i++)
#pragma unroll
        for (int j = 0; j < 2; j++) acc[i][j] = MFMA16(a[i], b[j], acc[i][j]);
    }
    __syncthreads();
  }

#pragma unroll
  for (int i = 0; i < 4; i++) {
#pragma unroll
    for (int j = 0; j < 2; j++) {
      const int col = nbase + wc * 32 + j * 16 + l15;
#pragma unroll
      for (int r = 0; r < 4; r++) {
        const int row = mbase + wr * 64 + i * 16 + l4 * 4 + r;
        float prev = first ? bias[col] : Y[(size_t)row * 512 + col];
        Y[(size_t)row * 512 + col] = prev + acc[i][j][r];
      }
    }
  }
}

extern "C" void kernel_launch(void* const* d_in, const int* in_sizes, int n_in,
                              void* d_out, int out_size, void* d_ws, size_t ws_size,
                              hipStream_t stream) {
  (void)in_sizes; (void)n_in; (void)out_size;
  const float* x = (const float*)d_in[0];
  const float* wq = (const float*)d_in[1];
  const float* wk = (const float*)d_in[2];
  const float* wv = (const float*)d_in[3];
  const float* wo = (const float*)d_in[4];
  const float* bo = (const float*)d_in[5];
  float* y = (float*)d_out;

  char* base = (char*)d_ws;
  size_t off = 0;
  auto alloc = [&](size_t bytes) -> void* {
    void* p = base + off;
    off += (bytes + 255) & ~(size_t)255;
    return p;
  };
  __bf16* xb = (__bf16*)alloc((size_t)8192 * 512 * 2);
  __bf16* wqb = (__bf16*)alloc((size_t)8 * 512 * 512 * 2);
  __bf16* wkb = (__bf16*)alloc((size_t)8 * 512 * 512 * 2);
  __bf16* wvb = (__bf16*)alloc((size_t)8 * 512 * 512 * 2);
  __bf16* wob = (__bf16*)alloc((size_t)512 * 4096 * 2);
  float* ct = (float*)alloc((size_t)2048 * 256 * 4);
  float* st = (float*)alloc((size_t)2048 * 256 * 4);
  const size_t persist = off;

  // choose largest head-group G with persist + 4 * (G*4*2048*512*2) <= ws_size
  int G = 0, lg = 0;
  for (int g = 8, l = 3; g >= 1; g >>= 1, --l) {
    size_t T = ((size_t)g * 4 * 2048 * 512 * 2 + 255) & ~(size_t)255;
    if (persist + 4 * T <= ws_size) { G = g; lg = l; break; }
  }
  if (G == 0) return;

  size_t T = ((size_t)G * 4 * 2048 * 512 * 2 + 255) & ~(size_t)255;
  __bf16* Qb = (__bf16*)(base + persist);
  __bf16* Kb = (__bf16*)(base + persist + T);
  __bf16* VTb = (__bf16*)(base + persist + 2 * T);
  __bf16* Ob = (__bf16*)(base + persist + 3 * T);

  prep_k<<<14336, 256, 0, stream>>>(x, wq, wk, wv, wo, xb, wqb, wkb, wvb, wob, ct, st);

  for (int h0 = 0; h0 < 8; h0 += G) {
    qkv_gemm_k<<<dim3(64, 4, 3 * G), 256, 0, stream>>>(xb, wqb, wkb, wvb, ct, st,
                                                       Qb, Kb, VTb, G, lg, h0);
    flash_attn_k<<<dim3(16, 4 * G), 512, 0, stream>>>(Qb, Kb, VTb, Ob, G, lg);
    out_gemm_k<<<dim3(64, 8), 256, 0, stream>>>(Ob, wob + h0 * 512, bo, y, G, h0 == 0);
  }
}